// Round 8
// baseline (646.034 us; speedup 1.0000x reference)
//
#include <hip/hip_runtime.h>

// ---------------- problem constants ----------------
#define BB   16
#define NN   512
#define DD   1024
#define NHH  16
#define DKK  64
#define DFF  4096
#define MM   (BB*NN)     // 8192 rows

typedef _Float16 h16;
typedef h16  h16x8 __attribute__((ext_vector_type(8)));
typedef h16  h16x4 __attribute__((ext_vector_type(4)));
typedef float f32x4 __attribute__((ext_vector_type(4)));

#define AS1 __attribute__((address_space(1)))
#define AS3 __attribute__((address_space(3)))

__device__ __forceinline__ void gld16(h16* lds_dst, const h16* g_src) {
  // async global->LDS, 16B per lane; LDS dest must be lane-linear (wave-uniform base + lane*16)
  __builtin_amdgcn_global_load_lds((const AS1 void*)g_src, (AS3 void*)lds_dst, 16, 0, 0);
}

// ---------------- LayerNorm row kernel: fp32 [rows][1024] -> f16 ----------------
__global__ __launch_bounds__(256) void ln_k(const float* __restrict__ in, h16* __restrict__ out)
{
  const int row = blockIdx.x;
  const int tid = threadIdx.x;
  const float4 v = ((const float4*)(in + (long)row * DD))[tid];
  float s  = v.x + v.y + v.z + v.w;
  float ss = v.x*v.x + v.y*v.y + v.z*v.z + v.w*v.w;
#pragma unroll
  for (int d = 32; d > 0; d >>= 1) { s += __shfl_down(s, d); ss += __shfl_down(ss, d); }
  __shared__ float red[8];
  const int wv = tid >> 6, ln = tid & 63;
  if (ln == 0) { red[wv] = s; red[4 + wv] = ss; }
  __syncthreads();
  s  = red[0] + red[1] + red[2] + red[3];
  ss = red[4] + red[5] + red[6] + red[7];
  const float mean = s * (1.0f / DD);
  const float var  = ss * (1.0f / DD) - mean * mean;
  const float rstd = rsqrtf(var + 1e-5f);
  h16x4 o;
  o[0] = (h16)((v.x - mean) * rstd);
  o[1] = (h16)((v.y - mean) * rstd);
  o[2] = (h16)((v.z - mean) * rstd);
  o[3] = (h16)((v.w - mean) * rstd);
  ((h16x4*)(out + (long)row * DD))[tid] = o;
}

// ---------------- transpose-cast: src fp32 [R][C] -> dst f16 [C][R], batched ----------------
__global__ __launch_bounds__(256) void tcast_k(const float* __restrict__ src, h16* __restrict__ dst,
                                               int R, int C, long sB, long dB)
{
  __shared__ float tile[32][33];
  const float* s = src + (long)blockIdx.z * sB;
  h16* d = dst + (long)blockIdx.z * dB;
  const int c0 = blockIdx.x * 32, r0 = blockIdx.y * 32;
  const int tx = threadIdx.x & 31, ty = threadIdx.x >> 5;   // 32 x 8
#pragma unroll
  for (int i = 0; i < 32; i += 8)
    tile[ty + i][tx] = s[(long)(r0 + ty + i) * C + c0 + tx];
  __syncthreads();
#pragma unroll
  for (int i = 0; i < 32; i += 8)
    d[(long)(c0 + ty + i) * R + r0 + tx] = (h16)tile[tx][ty + i];
}

// ---------------- split-K init: out[m][c] = bias[c] + add[m][c] (fp32, vectorized) ----------------
__global__ __launch_bounds__(256) void initadd_k(const float* __restrict__ add,
                                                 const float* __restrict__ bias,
                                                 float* __restrict__ out, int Nc4, long total4)
{
  for (long i = (long)blockIdx.x * 256 + threadIdx.x; i < total4; i += (long)gridDim.x * 256) {
    const float4 a = ((const float4*)add)[i];
    const float4 b = ((const float4*)bias)[i % Nc4];
    float4 o; o.x = a.x + b.x; o.y = a.y + b.y; o.z = a.z + b.z; o.w = a.w + b.w;
    ((float4*)out)[i] = o;
  }
}

// ---------------- f16 MFMA GEMM: C[M][Nc] = A[M][K] * Bt[Nc][K]^T ----------------
// depth-2 pipelined K-loop, 3 LDS bufs, counted vmcnt, single barrier per K-step,
// XOR-swizzled LDS, XCD-banded block remap. K = chunk length, ldk = row stride;
// blockIdx.z selects split-K chunk (A/Bt advanced by z*K).
// EPI 0: QK scatter (+bias)  EPI 1: x = C+bo+H  EPI 2: hff = relu(C+b1)
// EPI 3: out = C+b2+x        EPI 4: Vt scatter  EPI 5: split-K atomicAdd into of
template<int EPI>
__global__ __launch_bounds__(256) void gemm_k(
    const h16* __restrict__ A, const h16* __restrict__ Bt, int K, int ldk, int Nc,
    const float* __restrict__ bias0, const float* __restrict__ bias1,
    h16* __restrict__ o0, h16* __restrict__ o1,
    float* __restrict__ of, const float* __restrict__ addsrc)
{
  __shared__ h16 Asb[3 * 4096];   // 3 bufs x 128x32 f16 = 24 KB
  __shared__ h16 Bsb[3 * 4096];   // 24 KB
  const int tid  = threadIdx.x;
  const int wave = tid >> 6, lane = tid & 63;
  const int lr = lane & 15, lq = lane >> 4;

  A  += (long)blockIdx.z * K;     // split-K chunk offset
  Bt += (long)blockIdx.z * K;

  // XCD-banded remap: orig%8 ~ XCD (round-robin dispatch); band of Ny/8 m-panels
  // per XCD, n fastest within the band. Bijective (Ny % 8 == 0 for all launches).
  const int nxw = gridDim.x, nyw = gridDim.y;
  const int orig = blockIdx.x + nxw * blockIdx.y;
  const int xcd = orig & 7, sseq = orig >> 3;
  const int by = xcd * (nyw >> 3) + sseq / nxw;
  const int bx = sseq % nxw;
  const int m0 = by * 128, n0 = bx * 128;
  const int wr = (wave >> 1) * 64, wc = (wave & 1) * 64;

  // staging: chunk c (16B) -> LDS linear c*16; global slot XOR-swizzled
  const int c0 = tid,       r0 = c0 >> 2, s0 = ((c0 & 3) ^ ((c0 >> 3) & 3)) * 8;
  const int c1 = tid + 256, r1 = c1 >> 2, s1 = ((c1 & 3) ^ ((c1 >> 3) & 3)) * 8;

  // fragment read offsets (h16 elems): row*32 + (lq ^ ((row>>1)&3))*8
  int offA[4], offB[4];
#pragma unroll
  for (int i = 0; i < 4; ++i) {
    const int ra = wr + i * 16 + lr;
    const int rb = wc + i * 16 + lr;
    offA[i] = ra * 32 + (lq ^ ((ra >> 1) & 3)) * 8;
    offB[i] = rb * 32 + (lq ^ ((rb >> 1) & 3)) * 8;
  }

  f32x4 acc[4][4] = {};

  auto STAGE = [&](int k0, int bi) {
    h16* Ad = Asb + bi * 4096;
    h16* Bd = Bsb + bi * 4096;
    gld16(Ad + c0 * 8, A  + (long)(m0 + r0) * ldk + k0 + s0);
    gld16(Ad + c1 * 8, A  + (long)(m0 + r1) * ldk + k0 + s1);
    gld16(Bd + c0 * 8, Bt + (long)(n0 + r0) * ldk + k0 + s0);
    gld16(Bd + c1 * 8, Bt + (long)(n0 + r1) * ldk + k0 + s1);
  };

  const int nt = K >> 5;           // K/32 tiles (>=16 for all launches)
  STAGE(0, 0);
  STAGE(32, 1);
  int cur = 0;

  for (int t = 0; t < nt; ++t) {
    // drain my t-1 LDS reads (free) + wait tile t's loads; barrier = collective.
    asm volatile("s_waitcnt lgkmcnt(0)" ::: "memory");
    if (t + 1 < nt) asm volatile("s_waitcnt vmcnt(4)" ::: "memory");
    else            asm volatile("s_waitcnt vmcnt(0)" ::: "memory");
    __builtin_amdgcn_sched_barrier(0);
    __builtin_amdgcn_s_barrier();
    asm volatile("" ::: "memory");

    // prefetch t+2 into buf (t-1)%3: drained by everyone before this barrier.
    if (t + 2 < nt) STAGE((t + 2) << 5, (cur + 2) % 3);

    const h16* Ac = Asb + cur * 4096;
    const h16* Bc = Bsb + cur * 4096;
    h16x8 af[4], bf[4];
#pragma unroll
    for (int i = 0; i < 4; ++i) {
      af[i] = *(const h16x8*)(Ac + offA[i]);
      bf[i] = *(const h16x8*)(Bc + offB[i]);
    }
    __builtin_amdgcn_s_setprio(1);
#pragma unroll
    for (int i = 0; i < 4; ++i)
#pragma unroll
      for (int j = 0; j < 4; ++j)
        acc[i][j] = __builtin_amdgcn_mfma_f32_16x16x32_f16(af[i], bf[j], acc[i][j], 0, 0, 0);
    __builtin_amdgcn_s_setprio(0);

    cur = (cur == 2) ? 0 : cur + 1;
  }

  // epilogue: C/D layout row = (lane>>4)*4 + reg, col = lane&15
#pragma unroll
  for (int i = 0; i < 4; ++i) {
#pragma unroll
    for (int jn = 0; jn < 4; ++jn) {
#pragma unroll
      for (int j = 0; j < 4; ++j) {
        const int m   = m0 + wr + i * 16 + lq * 4 + j;
        const int col = n0 + wc + jn * 16 + lr;
        float v = acc[i][jn][j];
        if constexpr (EPI == 0) {
          const int w  = col >> 10;            // 0=Q 1=K (block-uniform)
          const int hh = (col >> 6) & 15, kk = col & 63;
          const int bidx = m >> 9, nq = m & 511;
          const int bcol = col & 1023;
          if (w == 0) o0[(((long)bidx * NHH + hh) * NN + nq) * DKK + kk] = (h16)(v + bias0[bcol]);
          else        o1[(((long)bidx * NHH + hh) * NN + nq) * DKK + kk] = (h16)(v + bias1[bcol]);
        } else if constexpr (EPI == 1) {
          of[(long)m * Nc + col] = v + bias0[col] + addsrc[(long)m * Nc + col];
        } else if constexpr (EPI == 2) {
          o0[(long)m * Nc + col] = (h16)fmaxf(v + bias0[col], 0.0f);
        } else if constexpr (EPI == 3) {
          of[(long)m * Nc + col] = v + bias0[col] + addsrc[(long)m * Nc + col];
        } else if constexpr (EPI == 4) {
          // m = h*64+kk (dk-row), col = token; coalesced over col
          const int bidx = col >> 9, nq = col & 511;
          o0[(((long)bidx * NHH + (m >> 6)) * DKK + (m & 63)) * NN + nq] = (h16)(v + bias0[m]);
        } else {
          atomicAdd(&of[(long)m * Nc + col], v);   // split-K partial
        }
      }
    }
  }
}

// ---------------- flash attention: per (b,h), 128 q-rows/block, 64-key chunks ----------------
// All LDS tiles XOR-swizzled: slot' = slot ^ (row&7). K/V ping-pong with
// single barrier per chunk (stage-after-barrier).
__global__ __launch_bounds__(256) void attn_k(
    const h16* __restrict__ Qh, const h16* __restrict__ Kh, const h16* __restrict__ Vt,
    const float* __restrict__ spm, h16* __restrict__ Oh)
{
  __shared__ h16 Qs[128 * 64];      // 16 KB
  __shared__ h16 Ks[2][64 * 64];    // 16 KB  [key][dk] ping-pong
  __shared__ h16 Vts[2][64 * 64];   // 16 KB  [dk][key] ping-pong
  __shared__ h16 Ps[4 * 32 * 64];   // 16 KB  per-wave P
  const int tid  = threadIdx.x;
  const int wave = tid >> 6, lane = tid & 63;
  const int lr = lane & 15, lq = lane >> 4;
  const int b = blockIdx.z, h = blockIdx.y;
  const int q0 = blockIdx.x * 128;
  const long bh = (long)b * NHH + h;
  const h16* Qg = Qh + bh * NN * DKK;
  const h16* Kg = Kh + bh * NN * DKK;
  const h16* Vg = Vt + bh * DKK * NN;

#pragma unroll
  for (int r = 0; r < 4; ++r) {               // stage 128x64 Q once (swizzled source)
    const int c = r * 256 + tid;
    const int row = c >> 3, sl = c & 7;
    gld16(Qs + c * 8, Qg + (long)(q0 + row) * DKK + ((sl ^ (row & 7)) * 8));
  }

  auto STAGEKV = [&](int kc, int bi) {
#pragma unroll
    for (int r = 0; r < 2; ++r) {
      const int c = r * 256 + tid;
      const int row = c >> 3, sl = c & 7;
      const int sg = (sl ^ (row & 7)) * 8;
      gld16(&Ks[bi][c * 8],  Kg + (long)(kc + row) * DKK + sg);
      gld16(&Vts[bi][c * 8], Vg + (long)row * NN + kc + sg);
    }
  };
  STAGEKV(0, 0);

  f32x4 acc[2][4] = {};
  float mrow[2][4], lsum[2][4];
#pragma unroll
  for (int a = 0; a < 2; ++a)
#pragma unroll
    for (int j = 0; j < 4; ++j) { mrow[a][j] = -3.0e38f; lsum[a][j] = 0.0f; }

  const int NT = NN / 64;   // 8 chunks
  for (int t = 0; t < NT; ++t) {
    const int kc = t * 64;
    asm volatile("s_waitcnt lgkmcnt(0)" ::: "memory");
    asm volatile("s_waitcnt vmcnt(0)" ::: "memory");
    __builtin_amdgcn_sched_barrier(0);
    __builtin_amdgcn_s_barrier();
    asm volatile("" ::: "memory");
    if (t + 1 < NT) STAGEKV(kc + 64, (t + 1) & 1);

    const h16* Kc = Ks[t & 1];
    const h16* Vc = Vts[t & 1];

    // S = Q K^T  (2 qm-frags x 4 kn-frags, DK=64 -> 2 mfma steps); swizzled reads
    f32x4 s[2][4] = {};
#pragma unroll
    for (int ks = 0; ks < 2; ++ks) {
      h16x8 aq[2], bk4[4];
#pragma unroll
      for (int qm = 0; qm < 2; ++qm) {
        const int row = wave * 32 + qm * 16 + lr;
        aq[qm] = *(const h16x8*)(Qs + row * 64 + ((ks * 4 + lq) ^ (row & 7)) * 8);
      }
#pragma unroll
      for (int kn = 0; kn < 4; ++kn) {
        const int row = kn * 16 + lr;
        bk4[kn] = *(const h16x8*)(Kc + row * 64 + ((ks * 4 + lq) ^ (row & 7)) * 8);
      }
      __builtin_amdgcn_s_setprio(1);
#pragma unroll
      for (int qm = 0; qm < 2; ++qm)
#pragma unroll
        for (int kn = 0; kn < 4; ++kn)
          s[qm][kn] = __builtin_amdgcn_mfma_f32_16x16x32_f16(aq[qm], bk4[kn], s[qm][kn], 0, 0, 0);
      __builtin_amdgcn_s_setprio(0);
    }

    // scale + spm bias, row-max
    float pm[2][4];
#pragma unroll
    for (int qm = 0; qm < 2; ++qm)
#pragma unroll
      for (int j = 0; j < 4; ++j) pm[qm][j] = -3.0e38f;
#pragma unroll
    for (int qm = 0; qm < 2; ++qm)
#pragma unroll
      for (int kn = 0; kn < 4; ++kn)
#pragma unroll
        for (int j = 0; j < 4; ++j) {
          const int q = q0 + wave * 32 + qm * 16 + lq * 4 + j;
          const int key = kc + kn * 16 + lr;
          float v = s[qm][kn][j] * 0.125f + spm[((long)b * NN + q) * NN + key];
          s[qm][kn][j] = v;
          pm[qm][j] = fmaxf(pm[qm][j], v);
        }
#pragma unroll
    for (int qm = 0; qm < 2; ++qm)
#pragma unroll
      for (int j = 0; j < 4; ++j) {
#pragma unroll
        for (int d = 1; d < 16; d <<= 1) pm[qm][j] = fmaxf(pm[qm][j], __shfl_xor(pm[qm][j], d));
      }
    // online-softmax update
    float corr[2][4];
#pragma unroll
    for (int qm = 0; qm < 2; ++qm)
#pragma unroll
      for (int j = 0; j < 4; ++j) {
        const float mn = fmaxf(mrow[qm][j], pm[qm][j]);
        corr[qm][j] = __expf(mrow[qm][j] - mn);
        mrow[qm][j] = mn;
        lsum[qm][j] *= corr[qm][j];
      }
    float rs[2][4] = {};
#pragma unroll
    for (int qm = 0; qm < 2; ++qm)
#pragma unroll
      for (int kn = 0; kn < 4; ++kn)
#pragma unroll
        for (int j = 0; j < 4; ++j) {
          const float pexp = __expf(s[qm][kn][j] - mrow[qm][j]);
          s[qm][kn][j] = pexp;
          rs[qm][j] += pexp;
        }
#pragma unroll
    for (int qm = 0; qm < 2; ++qm)
#pragma unroll
      for (int j = 0; j < 4; ++j) {
#pragma unroll
        for (int d = 1; d < 16; d <<= 1) rs[qm][j] += __shfl_xor(rs[qm][j], d);
        lsum[qm][j] += rs[qm][j];
      }
#pragma unroll
    for (int qm = 0; qm < 2; ++qm)
#pragma unroll
      for (int dn = 0; dn < 4; ++dn)
#pragma unroll
        for (int j = 0; j < 4; ++j) acc[qm][dn][j] *= corr[qm][j];

    // P (C-layout) -> LDS (swizzled) -> A-layout frags
#pragma unroll
    for (int qm = 0; qm < 2; ++qm)
#pragma unroll
      for (int kn = 0; kn < 4; ++kn)
#pragma unroll
        for (int j = 0; j < 4; ++j) {
          const int row = qm * 16 + lq * 4 + j;
          const int sl  = (kn * 2 + (lr >> 3)) ^ (row & 7);
          Ps[wave * 2048 + row * 64 + sl * 8 + (lr & 7)] = (h16)s[qm][kn][j];
        }

    // O += P @ V  (swizzled reads)
#pragma unroll
    for (int ks = 0; ks < 2; ++ks) {
      h16x8 ap[2], bv4[4];
#pragma unroll
      for (int qm = 0; qm < 2; ++qm) {
        const int row = qm * 16 + lr;
        ap[qm] = *(const h16x8*)(Ps + wave * 2048 + row * 64 + ((ks * 4 + lq) ^ (row & 7)) * 8);
      }
#pragma unroll
      for (int dn = 0; dn < 4; ++dn) {
        const int row = dn * 16 + lr;
        bv4[dn] = *(const h16x8*)(Vc + row * 64 + ((ks * 4 + lq) ^ (row & 7)) * 8);
      }
      __builtin_amdgcn_s_setprio(1);
#pragma unroll
      for (int qm = 0; qm < 2; ++qm)
#pragma unroll
        for (int dn = 0; dn < 4; ++dn)
          acc[qm][dn] = __builtin_amdgcn_mfma_f32_16x16x32_f16(ap[qm], bv4[dn], acc[qm][dn], 0, 0, 0);
      __builtin_amdgcn_s_setprio(0);
    }
  }

  // normalize + write O as [B,N,D] f16 (concat heads)
  float rinv[2][4];
#pragma unroll
  for (int qm = 0; qm < 2; ++qm)
#pragma unroll
    for (int j = 0; j < 4; ++j) rinv[qm][j] = 1.0f / lsum[qm][j];
#pragma unroll
  for (int qm = 0; qm < 2; ++qm)
#pragma unroll
    for (int dn = 0; dn < 4; ++dn)
#pragma unroll
      for (int j = 0; j < 4; ++j) {
        const int q = q0 + wave * 32 + qm * 16 + lq * 4 + j;
        const int dk = dn * 16 + lr;
        Oh[((long)b * NN + q) * DD + h * DKK + dk] = (h16)(acc[qm][dn][j] * rinv[qm][j]);
      }
}

// ---------------- launch ----------------
extern "C" void kernel_launch(void* const* d_in, const int* in_sizes, int n_in,
                              void* d_out, int out_size, void* d_ws, size_t ws_size,
                              hipStream_t stream)
{
  const float* H   = (const float*)d_in[0];
  const float* spm = (const float*)d_in[1];
  const float* Wq  = (const float*)d_in[2];
  const float* bq  = (const float*)d_in[3];
  const float* Wk  = (const float*)d_in[4];
  const float* bk  = (const float*)d_in[5];
  const float* Wv  = (const float*)d_in[6];
  const float* bv  = (const float*)d_in[7];
  const float* Wo  = (const float*)d_in[8];
  const float* bo  = (const float*)d_in[9];
  const float* W1  = (const float*)d_in[10];
  const float* b1  = (const float*)d_in[11];
  const float* W2  = (const float*)d_in[12];
  const float* b2  = (const float*)d_in[13];
  float* out = (float*)d_out;

  char* p = (char*)d_ws;
  auto alloc = [&](size_t bytes) { char* r = p; p += (bytes + 255) & ~(size_t)255; return r; };
  h16* ln1   = (h16*)alloc((size_t)MM * DD * 2);        // 16 MB (reused as ln2)
  h16* wqkv  = (h16*)alloc((size_t)3 * DD * DD * 2);    //  6 MB
  h16* wo_t  = (h16*)alloc((size_t)DD * DD * 2);        //  2 MB
  h16* w1_t  = (h16*)alloc((size_t)DD * DFF * 2);       //  8 MB
  h16* w2_t  = (h16*)alloc((size_t)DFF * DD * 2);       //  8 MB
  h16* Qh    = (h16*)alloc((size_t)MM * DD * 2);        // 16 MB (contig 64MB Qh..Oh)
  h16* Kh    = (h16*)alloc((size_t)MM * DD * 2);        // 16 MB
  h16* Vt    = (h16*)alloc((size_t)MM * DD * 2);        // 16 MB (reused as hff)
  h16* Oh    = (h16*)alloc((size_t)MM * DD * 2);        // 16 MB
  float* x   = (float*)alloc((size_t)MM * DD * 4);      // 32 MB
  h16* ln2 = ln1;                                       // alias (ln1 dead after QKV+VT GEMMs)
  h16* hff = Qh;                                        // alias (Q/K/V/O dead after Wo GEMM)

  // 1) LN1
  ln_k<<<MM, 256, 0, stream>>>(H, ln1);
  // 2) weight transpose-casts to f16 B^T layouts
  tcast_k<<<dim3(2, 32, 16),  256, 0, stream>>>(Wq, wqkv,                 DD, DKK, (long)DD * DKK, (long)DKK * DD);
  tcast_k<<<dim3(2, 32, 16),  256, 0, stream>>>(Wk, wqkv + DD * DD,       DD, DKK, (long)DD * DKK, (long)DKK * DD);
  tcast_k<<<dim3(2, 32, 16),  256, 0, stream>>>(Wv, wqkv + 2 * DD * DD,   DD, DKK, (long)DD * DKK, (long)DKK * DD);
  tcast_k<<<dim3(32, 32, 1),  256, 0, stream>>>(Wo, wo_t, DD,  DD,  0, 0);
  tcast_k<<<dim3(128, 32, 1), 256, 0, stream>>>(W1, w1_t, DD,  DFF, 0, 0);
  tcast_k<<<dim3(32, 128, 1), 256, 0, stream>>>(W2, w2_t, DFF, DD,  0, 0);
  // 3a) QK projection (scatters Q,K [b,h,n,dk])
  gemm_k<0><<<dim3(16, 64), 256, 0, stream>>>(ln1, wqkv, DD, DD, 2 * DD, bq, bk, Qh, Kh, nullptr, nullptr);
  // 3b) V^T projection: A = Wv^T-part [dk-rows=1024][d], Bt = ln1 -> Vt [b,h,dk,n] coalesced
  gemm_k<4><<<dim3(64, 8), 256, 0, stream>>>(wqkv + 2 * DD * DD, ln1, DD, DD, MM, bv, nullptr, Vt, nullptr, nullptr, nullptr);
  // 4) attention
  attn_k<<<dim3(4, NHH, BB), 256, 0, stream>>>(Qh, Kh, Vt, spm, Oh);
  // 5) Wo GEMM + residual -> x (fp32): x = bo + H, then split-K=2 atomic partials
  initadd_k<<<2048, 256, 0, stream>>>(H, bo, x, DD / 4, (long)MM * DD / 4);
  gemm_k<5><<<dim3(8, 64, 2), 256, 0, stream>>>(Oh, wo_t, DD / 2, DD, DD, nullptr, nullptr, nullptr, nullptr, x, nullptr);
  // 6) LN2
  ln_k<<<MM, 256, 0, stream>>>(x, ln2);
  // 7) FFN1 + ReLU -> hff (f16)
  gemm_k<2><<<dim3(32, 64), 256, 0, stream>>>(ln2, w1_t, DD, DD, DFF, b1, nullptr, hff, nullptr, nullptr, nullptr);
  // 8) FFN2 + residual -> out (fp32): out = b2 + x, then split-K=4 atomic partials
  initadd_k<<<2048, 256, 0, stream>>>(x, b2, out, DD / 4, (long)MM * DD / 4);
  gemm_k<5><<<dim3(8, 64, 4), 256, 0, stream>>>(hff, w2_t, DFF / 4, DFF, DD, nullptr, nullptr, nullptr, nullptr, out, nullptr);
}

// Round 9
// 495.239 us; speedup vs baseline: 1.3045x; 1.3045x over previous
//
#include <hip/hip_runtime.h>

// ---------------- problem constants ----------------
#define BB   16
#define NN   512
#define DD   1024
#define NHH  16
#define DKK  64
#define DFF  4096
#define MM   (BB*NN)     // 8192 rows

typedef _Float16 h16;
typedef h16  h16x8 __attribute__((ext_vector_type(8)));
typedef h16  h16x4 __attribute__((ext_vector_type(4)));
typedef float f32x4 __attribute__((ext_vector_type(4)));

#define AS1 __attribute__((address_space(1)))
#define AS3 __attribute__((address_space(3)))

__device__ __forceinline__ void gld16(h16* lds_dst, const h16* g_src) {
  // async global->LDS, 16B per lane; LDS dest must be lane-linear (wave-uniform base + lane*16)
  __builtin_amdgcn_global_load_lds((const AS1 void*)g_src, (AS3 void*)lds_dst, 16, 0, 0);
}

// ---------------- LayerNorm row kernel: fp32 [rows][1024] -> f16 ----------------
__global__ __launch_bounds__(256) void ln_k(const float* __restrict__ in, h16* __restrict__ out)
{
  const int row = blockIdx.x;
  const int tid = threadIdx.x;
  const float4 v = ((const float4*)(in + (long)row * DD))[tid];
  float s  = v.x + v.y + v.z + v.w;
  float ss = v.x*v.x + v.y*v.y + v.z*v.z + v.w*v.w;
#pragma unroll
  for (int d = 32; d > 0; d >>= 1) { s += __shfl_down(s, d); ss += __shfl_down(ss, d); }
  __shared__ float red[8];
  const int wv = tid >> 6, ln = tid & 63;
  if (ln == 0) { red[wv] = s; red[4 + wv] = ss; }
  __syncthreads();
  s  = red[0] + red[1] + red[2] + red[3];
  ss = red[4] + red[5] + red[6] + red[7];
  const float mean = s * (1.0f / DD);
  const float var  = ss * (1.0f / DD) - mean * mean;
  const float rstd = rsqrtf(var + 1e-5f);
  h16x4 o;
  o[0] = (h16)((v.x - mean) * rstd);
  o[1] = (h16)((v.y - mean) * rstd);
  o[2] = (h16)((v.z - mean) * rstd);
  o[3] = (h16)((v.w - mean) * rstd);
  ((h16x4*)(out + (long)row * DD))[tid] = o;
}

// ---------------- transpose-cast: src fp32 [R][C] -> dst f16 [C][R], batched ----------------
__global__ __launch_bounds__(256) void tcast_k(const float* __restrict__ src, h16* __restrict__ dst,
                                               int R, int C, long sB, long dB)
{
  __shared__ float tile[32][33];
  const float* s = src + (long)blockIdx.z * sB;
  h16* d = dst + (long)blockIdx.z * dB;
  const int c0 = blockIdx.x * 32, r0 = blockIdx.y * 32;
  const int tx = threadIdx.x & 31, ty = threadIdx.x >> 5;   // 32 x 8
#pragma unroll
  for (int i = 0; i < 32; i += 8)
    tile[ty + i][tx] = s[(long)(r0 + ty + i) * C + c0 + tx];
  __syncthreads();
#pragma unroll
  for (int i = 0; i < 32; i += 8)
    d[(long)(c0 + ty + i) * R + r0 + tx] = (h16)tile[tx][ty + i];
}

// ---------------- gemm_k: 128x128 tile, 4 waves (kept for FFN2 / Wo / VT) ----------------
// depth-2 pipelined K-loop, 3 LDS bufs, counted vmcnt, single barrier per K-step,
// XOR-swizzled LDS, XCD-banded block remap.
// EPI 1: x = C+bo+H   EPI 3: out = C+b2+x   EPI 4: Vt scatter
template<int EPI>
__global__ __launch_bounds__(256) void gemm_k(
    const h16* __restrict__ A, const h16* __restrict__ Bt, int K, int ldk, int Nc,
    const float* __restrict__ bias0, const float* __restrict__ bias1,
    h16* __restrict__ o0, h16* __restrict__ o1,
    float* __restrict__ of, const float* __restrict__ addsrc)
{
  __shared__ h16 Asb[3 * 4096];   // 3 bufs x 128x32 f16 = 24 KB
  __shared__ h16 Bsb[3 * 4096];   // 24 KB
  const int tid  = threadIdx.x;
  const int wave = tid >> 6, lane = tid & 63;
  const int lr = lane & 15, lq = lane >> 4;

  const int nxw = gridDim.x, nyw = gridDim.y;
  const int orig = blockIdx.x + nxw * blockIdx.y;
  int bx, by;
  if ((nyw & 7) == 0) {
    const int xcd = orig & 7, sseq = orig >> 3;
    by = xcd * (nyw >> 3) + sseq / nxw;
    bx = sseq % nxw;
  } else { bx = blockIdx.x; by = blockIdx.y; }
  const int m0 = by * 128, n0 = bx * 128;
  const int wr = (wave >> 1) * 64, wc = (wave & 1) * 64;

  const int c0 = tid,       r0 = c0 >> 2, s0 = ((c0 & 3) ^ ((c0 >> 3) & 3)) * 8;
  const int c1 = tid + 256, r1 = c1 >> 2, s1 = ((c1 & 3) ^ ((c1 >> 3) & 3)) * 8;

  int offA[4], offB[4];
#pragma unroll
  for (int i = 0; i < 4; ++i) {
    const int ra = wr + i * 16 + lr;
    const int rb = wc + i * 16 + lr;
    offA[i] = ra * 32 + (lq ^ ((ra >> 1) & 3)) * 8;
    offB[i] = rb * 32 + (lq ^ ((rb >> 1) & 3)) * 8;
  }

  f32x4 acc[4][4] = {};

  auto STAGE = [&](int k0, int bi) {
    h16* Ad = Asb + bi * 4096;
    h16* Bd = Bsb + bi * 4096;
    gld16(Ad + c0 * 8, A  + (long)(m0 + r0) * ldk + k0 + s0);
    gld16(Ad + c1 * 8, A  + (long)(m0 + r1) * ldk + k0 + s1);
    gld16(Bd + c0 * 8, Bt + (long)(n0 + r0) * ldk + k0 + s0);
    gld16(Bd + c1 * 8, Bt + (long)(n0 + r1) * ldk + k0 + s1);
  };

  const int nt = K >> 5;
  STAGE(0, 0);
  STAGE(32, 1);
  int cur = 0;

  for (int t = 0; t < nt; ++t) {
    asm volatile("s_waitcnt lgkmcnt(0)" ::: "memory");
    if (t + 1 < nt) asm volatile("s_waitcnt vmcnt(4)" ::: "memory");
    else            asm volatile("s_waitcnt vmcnt(0)" ::: "memory");
    __builtin_amdgcn_sched_barrier(0);
    __builtin_amdgcn_s_barrier();
    asm volatile("" ::: "memory");

    if (t + 2 < nt) STAGE((t + 2) << 5, (cur + 2) % 3);

    const h16* Ac = Asb + cur * 4096;
    const h16* Bc = Bsb + cur * 4096;
    h16x8 af[4], bf[4];
#pragma unroll
    for (int i = 0; i < 4; ++i) {
      af[i] = *(const h16x8*)(Ac + offA[i]);
      bf[i] = *(const h16x8*)(Bc + offB[i]);
    }
    __builtin_amdgcn_s_setprio(1);
#pragma unroll
    for (int i = 0; i < 4; ++i)
#pragma unroll
      for (int j = 0; j < 4; ++j)
        acc[i][j] = __builtin_amdgcn_mfma_f32_16x16x32_f16(af[i], bf[j], acc[i][j], 0, 0, 0);
    __builtin_amdgcn_s_setprio(0);

    cur = (cur == 2) ? 0 : cur + 1;
  }

#pragma unroll
  for (int i = 0; i < 4; ++i) {
#pragma unroll
    for (int jn = 0; jn < 4; ++jn) {
#pragma unroll
      for (int j = 0; j < 4; ++j) {
        const int m   = m0 + wr + i * 16 + lq * 4 + j;
        const int col = n0 + wc + jn * 16 + lr;
        float v = acc[i][jn][j];
        if constexpr (EPI == 1) {
          of[(long)m * Nc + col] = v + bias0[col] + addsrc[(long)m * Nc + col];
        } else if constexpr (EPI == 3) {
          of[(long)m * Nc + col] = v + bias0[col] + addsrc[(long)m * Nc + col];
        } else {
          // EPI 4: m = h*64+kk (dk-row), col = token; coalesced over col
          const int bidx = col >> 9, nq = col & 511;
          o0[(((long)bidx * NHH + (m >> 6)) * DKK + (m & 63)) * NN + nq] = (h16)(v + bias0[m]);
        }
      }
    }
  }
}

// ---------------- gemm8_k: 256x256 tile, 8 waves, 4-phase pipelined (FFN1 / QK) ----------------
// Per-wave 128x64 C (waves 2M x 4N). BK=64, 2 dbufs (128 KB LDS, 1 block/CU).
// 4 phases/K-tile: {frag ds_reads | stage one 16KB half-unit of tile t+1 | 16 MFMA | barrier}.
// vmcnt(0) only at tile top; A half-units staged first (phases 1-2) so HBM latency hides.
// EPI 0: QK scatter (+bias)   EPI 2: o0 = relu(C+bias) f16
template<int EPI>
__global__ __launch_bounds__(512, 2) void gemm8_k(
    const h16* __restrict__ A, const h16* __restrict__ Bt, int K, int ldk, int Nc,
    const float* __restrict__ bias0, const float* __restrict__ bias1,
    h16* __restrict__ o0, h16* __restrict__ o1)
{
  __shared__ h16 As[2][2][128 * 64];   // 64 KB: [dbuf][half][128 rows x 64 k]
  __shared__ h16 Bs[2][2][128 * 64];   // 64 KB
  const int tid  = threadIdx.x;
  const int wave = tid >> 6, lane = tid & 63;
  const int lr = lane & 15, lq = lane >> 4;

  const int nxw = gridDim.x, nyw = gridDim.y;
  const int orig = blockIdx.x + nxw * blockIdx.y;
  int bx, by;
  if ((nyw & 7) == 0) {
    const int xcd = orig & 7, sseq = orig >> 3;
    by = xcd * (nyw >> 3) + sseq / nxw;
    bx = sseq % nxw;
  } else { bx = blockIdx.x; by = blockIdx.y; }
  const int m0 = by * 256, n0 = bx * 256;
  const int wr = (wave >> 2) * 128;        // 0 or 128
  const int wc = (wave & 3) * 64;          // 0,64,128,192
  const int ah = wr >> 7;                  // wave's fixed A half

  // staging: half-unit = 128 rows x 64 k = 16KB = 2 chunks/thread, lane-linear LDS dest
  auto SA = [&](int k0, int dbf, int hf) {
    h16* dst = &As[dbf][hf][0];
    const h16* src = A + (long)(m0 + hf * 128) * ldk + k0;
#pragma unroll
    for (int j = 0; j < 2; ++j) {
      const int c = tid + j * 512;
      const int row = c >> 3;
      const int sl = ((c & 7) ^ (row & 7)) * 8;
      gld16(dst + c * 8, src + (long)row * ldk + sl);
    }
  };
  auto SB = [&](int k0, int dbf, int hf) {
    h16* dst = &Bs[dbf][hf][0];
    const h16* src = Bt + (long)(n0 + hf * 128) * ldk + k0;
#pragma unroll
    for (int j = 0; j < 2; ++j) {
      const int c = tid + j * 512;
      const int row = c >> 3;
      const int sl = ((c & 7) ^ (row & 7)) * 8;
      gld16(dst + c * 8, src + (long)row * ldk + sl);
    }
  };

  // fragment read offsets: slot = (ks*4+lq)^(lr&7); row&7 == lr&7 for all frags
  const int sl0 = (lq ^ (lr & 7)) * 8, sl1 = sl0 ^ 32;
  int brow[4];
#pragma unroll
  for (int jn = 0; jn < 4; ++jn) brow[jn] = wc + jn * 16 + lr;  // 0..255

  f32x4 acc[8][4] = {};
  h16x8 a[4][2], b[4][2];

  auto RDA = [&](int d, int mh) {     // 8 reads: a-frags for quadrant mh
#pragma unroll
    for (int ii = 0; ii < 4; ++ii) {
      const int ro = (mh * 64 + ii * 16 + lr) * 64;
      a[ii][0] = *(const h16x8*)&As[d][ah][ro + sl0];
      a[ii][1] = *(const h16x8*)&As[d][ah][ro + sl1];
    }
  };
  auto RDB = [&](int d, int j0) {     // 4 reads: b-frags jn = j0, j0+1
#pragma unroll
    for (int jj = 0; jj < 2; ++jj) {
      const int rb = brow[j0 + jj];
      const int ro = (rb & 127) * 64;
      b[j0 + jj][0] = *(const h16x8*)&Bs[d][rb >> 7][ro + sl0];
      b[j0 + jj][1] = *(const h16x8*)&Bs[d][rb >> 7][ro + sl1];
    }
  };

#define MF16(MH, J0)                                                                   \
  __builtin_amdgcn_s_setprio(1);                                                       \
  _Pragma("unroll")                                                                    \
  for (int ii = 0; ii < 4; ++ii)                                                       \
    _Pragma("unroll")                                                                  \
    for (int jj = 0; jj < 2; ++jj)                                                     \
      _Pragma("unroll")                                                                \
      for (int ks = 0; ks < 2; ++ks)                                                   \
        acc[(MH)*4 + ii][(J0) + jj] = __builtin_amdgcn_mfma_f32_16x16x32_f16(          \
            a[ii][ks], b[(J0) + jj][ks], acc[(MH)*4 + ii][(J0) + jj], 0, 0, 0);        \
  __builtin_amdgcn_s_setprio(0);

  const int nt = K >> 6;
  // prologue: tile 0 fully staged into dbuf 0
  SA(0, 0, 0); SA(0, 0, 1); SB(0, 0, 0); SB(0, 0, 1);

  for (int t = 0; t < nt; ++t) {
    const int d = t & 1, nd = d ^ 1;
    const int kn = (t + 1) << 6;
    const bool more = (t + 1) < nt;

    // tile top: all of tile t's units landed (per-wave) + collective barrier
    asm volatile("s_waitcnt vmcnt(0)" ::: "memory");
    __builtin_amdgcn_sched_barrier(0);
    __builtin_amdgcn_s_barrier();
    asm volatile("" ::: "memory");

    // phase 1: quadrant (mh0, n 0-1); stage A-h0 of t+1
    RDA(d, 0); RDB(d, 0);
    if (more) SA(kn, nd, 0);
    MF16(0, 0)
    __builtin_amdgcn_s_barrier();
    // phase 2: (mh0, n 2-3); stage A-h1
    RDB(d, 2);
    if (more) SA(kn, nd, 1);
    MF16(0, 2)
    __builtin_amdgcn_s_barrier();
    // phase 3: (mh1, n 0-1); stage B-h0
    RDA(d, 1);
    if (more) SB(kn, nd, 0);
    MF16(1, 0)
    __builtin_amdgcn_s_barrier();
    // phase 4: (mh1, n 2-3); stage B-h1
    if (more) SB(kn, nd, 1);
    MF16(1, 2)
    // next tile-top barrier closes the phase
  }
#undef MF16

  // epilogue: C/D row = (lane>>4)*4 + reg, col = lane&15
#pragma unroll
  for (int i = 0; i < 8; ++i) {
#pragma unroll
    for (int jn = 0; jn < 4; ++jn) {
#pragma unroll
      for (int j = 0; j < 4; ++j) {
        const int m   = m0 + wr + i * 16 + lq * 4 + j;
        const int col = n0 + wc + jn * 16 + lr;
        float v = acc[i][jn][j];
        if constexpr (EPI == 0) {
          const int w  = col >> 10;            // 0=Q 1=K (uniform per col-frag)
          const int hh = (col >> 6) & 15, kk = col & 63;
          const int bidx = m >> 9, nq = m & 511;
          const int bcol = col & 1023;
          if (w == 0) o0[(((long)bidx * NHH + hh) * NN + nq) * DKK + kk] = (h16)(v + bias0[bcol]);
          else        o1[(((long)bidx * NHH + hh) * NN + nq) * DKK + kk] = (h16)(v + bias1[bcol]);
        } else {
          o0[(long)m * Nc + col] = (h16)fmaxf(v + bias0[col], 0.0f);
        }
      }
    }
  }
}

// ---------------- flash attention: per (b,h), 128 q-rows/block, 64-key chunks ----------------
__global__ __launch_bounds__(256) void attn_k(
    const h16* __restrict__ Qh, const h16* __restrict__ Kh, const h16* __restrict__ Vt,
    const float* __restrict__ spm, h16* __restrict__ Oh)
{
  __shared__ h16 Qs[128 * 64];
  __shared__ h16 Ks[2][64 * 64];
  __shared__ h16 Vts[2][64 * 64];
  __shared__ h16 Ps[4 * 32 * 64];
  const int tid  = threadIdx.x;
  const int wave = tid >> 6, lane = tid & 63;
  const int lr = lane & 15, lq = lane >> 4;
  const int b = blockIdx.z, h = blockIdx.y;
  const int q0 = blockIdx.x * 128;
  const long bh = (long)b * NHH + h;
  const h16* Qg = Qh + bh * NN * DKK;
  const h16* Kg = Kh + bh * NN * DKK;
  const h16* Vg = Vt + bh * DKK * NN;

#pragma unroll
  for (int r = 0; r < 4; ++r) {
    const int c = r * 256 + tid;
    const int row = c >> 3, sl = c & 7;
    gld16(Qs + c * 8, Qg + (long)(q0 + row) * DKK + ((sl ^ (row & 7)) * 8));
  }

  auto STAGEKV = [&](int kc, int bi) {
#pragma unroll
    for (int r = 0; r < 2; ++r) {
      const int c = r * 256 + tid;
      const int row = c >> 3, sl = c & 7;
      const int sg = (sl ^ (row & 7)) * 8;
      gld16(&Ks[bi][c * 8],  Kg + (long)(kc + row) * DKK + sg);
      gld16(&Vts[bi][c * 8], Vg + (long)row * NN + kc + sg);
    }
  };
  STAGEKV(0, 0);

  f32x4 acc[2][4] = {};
  float mrow[2][4], lsum[2][4];
#pragma unroll
  for (int a = 0; a < 2; ++a)
#pragma unroll
    for (int j = 0; j < 4; ++j) { mrow[a][j] = -3.0e38f; lsum[a][j] = 0.0f; }

  const int NT = NN / 64;
  for (int t = 0; t < NT; ++t) {
    const int kc = t * 64;
    asm volatile("s_waitcnt lgkmcnt(0)" ::: "memory");
    asm volatile("s_waitcnt vmcnt(0)" ::: "memory");
    __builtin_amdgcn_sched_barrier(0);
    __builtin_amdgcn_s_barrier();
    asm volatile("" ::: "memory");
    if (t + 1 < NT) STAGEKV(kc + 64, (t + 1) & 1);

    const h16* Kc = Ks[t & 1];
    const h16* Vc = Vts[t & 1];

    f32x4 s[2][4] = {};
#pragma unroll
    for (int ks = 0; ks < 2; ++ks) {
      h16x8 aq[2], bk4[4];
#pragma unroll
      for (int qm = 0; qm < 2; ++qm) {
        const int row = wave * 32 + qm * 16 + lr;
        aq[qm] = *(const h16x8*)(Qs + row * 64 + ((ks * 4 + lq) ^ (row & 7)) * 8);
      }
#pragma unroll
      for (int kn = 0; kn < 4; ++kn) {
        const int row = kn * 16 + lr;
        bk4[kn] = *(const h16x8*)(Kc + row * 64 + ((ks * 4 + lq) ^ (row & 7)) * 8);
      }
      __builtin_amdgcn_s_setprio(1);
#pragma unroll
      for (int qm = 0; qm < 2; ++qm)
#pragma unroll
        for (int kn = 0; kn < 4; ++kn)
          s[qm][kn] = __builtin_amdgcn_mfma_f32_16x16x32_f16(aq[qm], bk4[kn], s[qm][kn], 0, 0, 0);
      __builtin_amdgcn_s_setprio(0);
    }

    float pm[2][4];
#pragma unroll
    for (int qm = 0; qm < 2; ++qm)
#pragma unroll
      for (int j = 0; j < 4; ++j) pm[qm][j] = -3.0e38f;
#pragma unroll
    for (int qm = 0; qm < 2; ++qm)
#pragma unroll
      for (int kn = 0; kn < 4; ++kn)
#pragma unroll
        for (int j = 0; j < 4; ++j) {
          const int q = q0 + wave * 32 + qm * 16 + lq * 4 + j;
          const int key = kc + kn * 16 + lr;
          float v = s[qm][kn][j] * 0.125f + spm[((long)b * NN + q) * NN + key];
          s[qm][kn][j] = v;
          pm[qm][j] = fmaxf(pm[qm][j], v);
        }
#pragma unroll
    for (int qm = 0; qm < 2; ++qm)
#pragma unroll
      for (int j = 0; j < 4; ++j) {
#pragma unroll
        for (int d = 1; d < 16; d <<= 1) pm[qm][j] = fmaxf(pm[qm][j], __shfl_xor(pm[qm][j], d));
      }
    float corr[2][4];
#pragma unroll
    for (int qm = 0; qm < 2; ++qm)
#pragma unroll
      for (int j = 0; j < 4; ++j) {
        const float mn = fmaxf(mrow[qm][j], pm[qm][j]);
        corr[qm][j] = __expf(mrow[qm][j] - mn);
        mrow[qm][j] = mn;
        lsum[qm][j] *= corr[qm][j];
      }
    float rs[2][4] = {};
#pragma unroll
    for (int qm = 0; qm < 2; ++qm)
#pragma unroll
      for (int kn = 0; kn < 4; ++kn)
#pragma unroll
        for (int j = 0; j < 4; ++j) {
          const float pexp = __expf(s[qm][kn][j] - mrow[qm][j]);
          s[qm][kn][j] = pexp;
          rs[qm][j] += pexp;
        }
#pragma unroll
    for (int qm = 0; qm < 2; ++qm)
#pragma unroll
      for (int j = 0; j < 4; ++j) {
#pragma unroll
        for (int d = 1; d < 16; d <<= 1) rs[qm][j] += __shfl_xor(rs[qm][j], d);
        lsum[qm][j] += rs[qm][j];
      }
#pragma unroll
    for (int qm = 0; qm < 2; ++qm)
#pragma unroll
      for (int dn = 0; dn < 4; ++dn)
#pragma unroll
        for (int j = 0; j < 4; ++j) acc[qm][dn][j] *= corr[qm][j];

#pragma unroll
    for (int qm = 0; qm < 2; ++qm)
#pragma unroll
      for (int kn = 0; kn < 4; ++kn)
#pragma unroll
        for (int j = 0; j < 4; ++j) {
          const int row = qm * 16 + lq * 4 + j;
          const int sl  = (kn * 2 + (lr >> 3)) ^ (row & 7);
          Ps[wave * 2048 + row * 64 + sl * 8 + (lr & 7)] = (h16)s[qm][kn][j];
        }

#pragma unroll
    for (int ks = 0; ks < 2; ++ks) {
      h16x8 ap[2], bv4[4];
#pragma unroll
      for (int qm = 0; qm < 2; ++qm) {
        const int row = qm * 16 + lr;
        ap[qm] = *(const h16x8*)(Ps + wave * 2048 + row * 64 + ((ks * 4 + lq) ^ (row & 7)) * 8);
      }
#pragma unroll
      for (int dn = 0; dn < 4; ++dn) {
        const int row = dn * 16 + lr;
        bv4[dn] = *(const h16x8*)(Vc + row * 64 + ((ks * 4 + lq) ^ (row & 7)) * 8);
      }
      __builtin_amdgcn_s_setprio(1);
#pragma unroll
      for (int qm = 0; qm < 2; ++qm)
#pragma unroll
        for (int dn = 0; dn < 4; ++dn)
          acc[qm][dn] = __builtin_amdgcn_mfma_f32_16x16x32_f16(ap[qm], bv4[dn], acc[qm][dn], 0, 0, 0);
      __builtin_amdgcn_s_setprio(0);
    }
  }

  float rinv[2][4];
#pragma unroll
  for (int qm = 0; qm < 2; ++qm)
#pragma unroll
    for (int j = 0; j < 4; ++j) rinv[qm][j] = 1.0f / lsum[qm][j];
#pragma unroll
  for (int qm = 0; qm < 2; ++qm)
#pragma unroll
    for (int dn = 0; dn < 4; ++dn)
#pragma unroll
      for (int j = 0; j < 4; ++j) {
        const int q = q0 + wave * 32 + qm * 16 + lq * 4 + j;
        const int dk = dn * 16 + lr;
        Oh[((long)b * NN + q) * DD + h * DKK + dk] = (h16)(acc[qm][dn][j] * rinv[qm][j]);
      }
}

// ---------------- launch ----------------
extern "C" void kernel_launch(void* const* d_in, const int* in_sizes, int n_in,
                              void* d_out, int out_size, void* d_ws, size_t ws_size,
                              hipStream_t stream)
{
  const float* H   = (const float*)d_in[0];
  const float* spm = (const float*)d_in[1];
  const float* Wq  = (const float*)d_in[2];
  const float* bq  = (const float*)d_in[3];
  const float* Wk  = (const float*)d_in[4];
  const float* bk  = (const float*)d_in[5];
  const float* Wv  = (const float*)d_in[6];
  const float* bv  = (const float*)d_in[7];
  const float* Wo  = (const float*)d_in[8];
  const float* bo  = (const float*)d_in[9];
  const float* W1  = (const float*)d_in[10];
  const float* b1  = (const float*)d_in[11];
  const float* W2  = (const float*)d_in[12];
  const float* b2  = (const float*)d_in[13];
  float* out = (float*)d_out;

  char* p = (char*)d_ws;
  auto alloc = [&](size_t bytes) { char* r = p; p += (bytes + 255) & ~(size_t)255; return r; };
  h16* ln1   = (h16*)alloc((size_t)MM * DD * 2);        // 16 MB (reused as ln2)
  h16* wqkv  = (h16*)alloc((size_t)3 * DD * DD * 2);    //  6 MB
  h16* wo_t  = (h16*)alloc((size_t)DD * DD * 2);        //  2 MB
  h16* w1_t  = (h16*)alloc((size_t)DD * DFF * 2);       //  8 MB
  h16* w2_t  = (h16*)alloc((size_t)DFF * DD * 2);       //  8 MB
  h16* Qh    = (h16*)alloc((size_t)MM * DD * 2);        // 16 MB
  h16* Kh    = (h16*)alloc((size_t)MM * DD * 2);        // 16 MB
  h16* Vt    = (h16*)alloc((size_t)MM * DD * 2);        // 16 MB (reused as hff)
  h16* Oh    = (h16*)alloc((size_t)MM * DD * 2);        // 16 MB
  float* x   = (float*)alloc((size_t)MM * DD * 4);      // 32 MB
  h16* ln2 = ln1;
  h16* hff = Qh;

  // 1) LN1
  ln_k<<<MM, 256, 0, stream>>>(H, ln1);
  // 2) weight transpose-casts
  tcast_k<<<dim3(2, 32, 16),  256, 0, stream>>>(Wq, wqkv,                 DD, DKK, (long)DD * DKK, (long)DKK * DD);
  tcast_k<<<dim3(2, 32, 16),  256, 0, stream>>>(Wk, wqkv + DD * DD,       DD, DKK, (long)DD * DKK, (long)DKK * DD);
  tcast_k<<<dim3(2, 32, 16),  256, 0, stream>>>(Wv, wqkv + 2 * DD * DD,   DD, DKK, (long)DD * DKK, (long)DKK * DD);
  tcast_k<<<dim3(32, 32, 1),  256, 0, stream>>>(Wo, wo_t, DD,  DD,  0, 0);
  tcast_k<<<dim3(128, 32, 1), 256, 0, stream>>>(W1, w1_t, DD,  DFF, 0, 0);
  tcast_k<<<dim3(32, 128, 1), 256, 0, stream>>>(W2, w2_t, DFF, DD,  0, 0);
  // 3a) QK projection (gemm8: 256x256, scatters Q,K [b,h,n,dk])
  gemm8_k<0><<<dim3(8, 32), 512, 0, stream>>>(ln1, wqkv, DD, DD, 2 * DD, bq, bk, Qh, Kh);
  // 3b) V^T projection (gemm_k: Vt [b,h,dk,n] coalesced)
  gemm_k<4><<<dim3(64, 8), 256, 0, stream>>>(wqkv + 2 * DD * DD, ln1, DD, DD, MM, bv, nullptr, Vt, nullptr, nullptr, nullptr);
  // 4) attention
  attn_k<<<dim3(4, NHH, BB), 256, 0, stream>>>(Qh, Kh, Vt, spm, Oh);
  // 5) Wo GEMM + residual -> x (fp32)
  gemm_k<1><<<dim3(8, 64), 256, 0, stream>>>(Oh, wo_t, DD, DD, DD, bo, nullptr, nullptr, nullptr, x, H);
  // 6) LN2
  ln_k<<<MM, 256, 0, stream>>>(x, ln2);
  // 7) FFN1 + ReLU -> hff (gemm8)
  gemm8_k<2><<<dim3(16, 32), 512, 0, stream>>>(ln2, w1_t, DD, DD, DFF, b1, nullptr, hff, nullptr);
  // 8) FFN2 + residual -> out (gemm_k)
  gemm_k<3><<<dim3(8, 64), 256, 0, stream>>>(hff, w2_t, DFF, DFF, DD, b2, nullptr, nullptr, nullptr, out, x);
}